// Round 5
// baseline (103.621 us; speedup 1.0000x reference)
//
#include <hip/hip_runtime.h>

// Int4 weight-only embedding: out[b,s,:] = (weight[x[b,s],:] - zp_group) * scale_group
// V=128000, D=2048, G=32 (64 groups/row), B*S=32768 tokens.
// weight int4-in-int32 [V,D]; scale f32 [V,64]; zp int32 [V,64]; x int32 [B*S].
// Output f32. Memory-bound gather.
//
// Round 4 -> 5: explicit register double-buffer with strict VMEM issue order:
// per iteration, issue next token's loads FIRST, then compute+nt-store current.
// vmcnt retires in issue order, so load-data waits never have to drain the
// (slow) nontemporal store acks. Index prefetch 2 tokens ahead.

#define DIM 2048
#define NGROUPS 64   // D / G

typedef float  f32x4 __attribute__((ext_vector_type(4)));
typedef int    i32x4 __attribute__((ext_vector_type(4)));

__global__ __launch_bounds__(256) void int4_embed_dequant_kernel(
    const int* __restrict__ weight,    // [V, D] int32 (int4 values)
    const float* __restrict__ scale,   // [V, 64] f32
    const int* __restrict__ zp,        // [V, 64] int32
    const int* __restrict__ x,         // [n_tokens] int32
    float* __restrict__ out,           // [n_tokens, D] f32
    int n_tokens)
{
    const int t = threadIdx.x;          // 256 threads, 8 channels each
    const int g = t >> 2;               // quant group = (t*8)/32
    const int stride = gridDim.x;
    const int woff = t << 1;            // offset in i32x4 units within a row

    int tok0 = blockIdx.x;
    if (tok0 >= n_tokens) return;

    // ---- prologue: current token's data + next token's index ----
    int row0 = x[tok0];
    i32x4 w0a, w0b; float s0, z0;
    {
        const size_t sr = (size_t)row0 * NGROUPS + g;
        s0 = scale[sr];
        z0 = (float)zp[sr];
        const i32x4* wr = (const i32x4*)weight + (size_t)row0 * (DIM / 4) + woff;
        w0a = wr[0];
        w0b = wr[1];
    }
    int tok1 = tok0 + stride;
    int row1 = (tok1 < n_tokens) ? x[tok1] : 0;

    while (true) {
        // ---- 1) issue NEXT token's data loads (before any store) ----
        i32x4 w1a = {0,0,0,0}, w1b = {0,0,0,0};
        float s1 = 0.f, z1 = 0.f;
        if (tok1 < n_tokens) {
            const size_t sr = (size_t)row1 * NGROUPS + g;
            s1 = scale[sr];
            z1 = (float)zp[sr];
            const i32x4* wr = (const i32x4*)weight + (size_t)row1 * (DIM / 4) + woff;
            w1a = wr[0];
            w1b = wr[1];
        }
        // ---- 2) prefetch index two tokens ahead ----
        const int tok2 = tok1 + stride;
        const int row2 = (tok2 < n_tokens) ? x[tok2] : 0;

        // ---- 3) compute + nt-store CURRENT token ----
        f32x4 o0, o1;
        o0.x = ((float)w0a.x - z0) * s0;
        o0.y = ((float)w0a.y - z0) * s0;
        o0.z = ((float)w0a.z - z0) * s0;
        o0.w = ((float)w0a.w - z0) * s0;
        o1.x = ((float)w0b.x - z0) * s0;
        o1.y = ((float)w0b.y - z0) * s0;
        o1.z = ((float)w0b.z - z0) * s0;
        o1.w = ((float)w0b.w - z0) * s0;

        f32x4* orow = (f32x4*)out + (size_t)tok0 * (DIM / 4) + woff;
        __builtin_nontemporal_store(o0, orow);
        __builtin_nontemporal_store(o1, orow + 1);

        if (tok1 >= n_tokens) break;

        // ---- 4) rotate pipeline registers ----
        tok0 = tok1; row0 = row1;
        w0a = w1a; w0b = w1b; s0 = s1; z0 = z1;
        tok1 = tok2; row1 = row2;
    }
}

extern "C" void kernel_launch(void* const* d_in, const int* in_sizes, int n_in,
                              void* d_out, int out_size, void* d_ws, size_t ws_size,
                              hipStream_t stream) {
    const int* weight  = (const int*)d_in[0];    // [V, D]
    const float* scale = (const float*)d_in[1];  // [V, 64]
    const int* zp      = (const int*)d_in[2];    // [V, 64]
    const int* x       = (const int*)d_in[3];    // [B*S]

    float* out = (float*)d_out;

    const int n_tokens = in_sizes[3];            // B*S = 32768

    // persistent grid: 8 blocks/CU * 256 CU = 2048 -> one residency wave,
    // each block walks 16 tokens.
    int grid = 2048;
    if (grid > n_tokens) grid = n_tokens;

    int4_embed_dequant_kernel<<<dim3(grid), dim3(256), 0, stream>>>(
        weight, scale, zp, x, out, n_tokens);
}

// Round 6
// 88.413 us; speedup vs baseline: 1.1720x; 1.1720x over previous
//
#include <hip/hip_runtime.h>

// Int4 weight-only embedding: out[b,s,:] = (weight[x[b,s],:] - zp_group) * scale_group
// V=128000, D=2048, G=32 (64 groups/row), B*S=32768 tokens.
// weight int4-in-int32 [V,D]; scale f32 [V,64]; zp int32 [V,64]; x int32 [B*S].
// Output f32. Memory-bound gather.
//
// Round 5 -> 6: one WAVE per token (was: one block per token).
//  - 4x more independent row-streams in flight per CU (32 vs 8) for the random
//    read side; 8x16B weight loads in flight per lane per token.
//  - scale/zp: lane==group, one coalesced 4B load each (64 groups = 64 lanes),
//    redistributed to consumers via __shfl (16 VALU shuffles/token) instead of
//    2 broadcast VMEM loads per wave.
//  - nontemporal 16B output stores kept; index prefetched one token ahead.

#define DIM 2048

typedef float  f32x4 __attribute__((ext_vector_type(4)));
typedef int    i32x4 __attribute__((ext_vector_type(4)));

__global__ __launch_bounds__(256) void int4_embed_dequant_kernel(
    const int* __restrict__ weight,    // [V, D] int32 (int4 values)
    const float* __restrict__ scale,   // [V, 64] f32
    const int* __restrict__ zp,        // [V, 64] int32
    const int* __restrict__ x,         // [n_tokens] int32
    float* __restrict__ out,           // [n_tokens, D] f32
    int n_tokens)
{
    const int lane = threadIdx.x & 63;
    const int wid  = (blockIdx.x << 2) + (threadIdx.x >> 6);  // global wave id
    const int nw   = gridDim.x << 2;                          // total waves

    int tok = wid;
    if (tok >= n_tokens) return;
    int row = x[tok];                   // wave-uniform broadcast load

    while (tok < n_tokens) {
        const int ntok = tok + nw;
        const int nrow = (ntok < n_tokens) ? x[ntok] : 0;  // prefetch next index

        // per-lane quant params: lane == group (64 groups/row, 64 lanes)
        const size_t sbase = (size_t)row * 64 + lane;
        const float s_my = scale[sbase];
        const float z_my = (float)zp[sbase];

        // 8 coalesced 16B loads: chunk k covers elems [k*256 + lane*4, +4)
        const i32x4* __restrict__ wr =
            (const i32x4*)weight + (size_t)row * (DIM / 4) + lane;
        i32x4 wv[8];
#pragma unroll
        for (int k = 0; k < 8; ++k) wv[k] = wr[k * 64];

        f32x4* orow = (f32x4*)out + (size_t)tok * (DIM / 4) + lane;
#pragma unroll
        for (int k = 0; k < 8; ++k) {
            // group of elem (k*256 + lane*4) = k*8 + lane/8 -> fetch from that lane
            const int src = (k << 3) + (lane >> 3);
            const float sk = __shfl(s_my, src);
            const float zk = __shfl(z_my, src);
            f32x4 o;
            o.x = ((float)wv[k].x - zk) * sk;
            o.y = ((float)wv[k].y - zk) * sk;
            o.z = ((float)wv[k].z - zk) * sk;
            o.w = ((float)wv[k].w - zk) * sk;
            __builtin_nontemporal_store(o, orow + k * 64);
        }

        tok = ntok;
        row = nrow;
    }
}

extern "C" void kernel_launch(void* const* d_in, const int* in_sizes, int n_in,
                              void* d_out, int out_size, void* d_ws, size_t ws_size,
                              hipStream_t stream) {
    const int* weight  = (const int*)d_in[0];    // [V, D]
    const float* scale = (const float*)d_in[1];  // [V, 64]
    const int* zp      = (const int*)d_in[2];    // [V, 64]
    const int* x       = (const int*)d_in[3];    // [B*S]

    float* out = (float*)d_out;

    const int n_tokens = in_sizes[3];            // B*S = 32768

    // 2048 blocks * 4 waves = 8192 independent token streams, 4 tokens each.
    int grid = 2048;
    int needed = (n_tokens + 3) / 4;
    if (grid > needed) grid = needed;

    int4_embed_dequant_kernel<<<dim3(grid), dim3(256), 0, stream>>>(
        weight, scale, zp, x, out, n_tokens);
}